// Round 13
// baseline (1999.376 us; speedup 1.0000x reference)
//
#include <hip/hip_runtime.h>
#include <hip/hip_cooperative_groups.h>

namespace cg = cooperative_groups;

// LSTM S=512,B=128,IN=256,H=512 — persistent kernel, 256 blocks =
// 8 rowgroups(16 batch rows) x 32 colgroups(16 hidden cols; 4 gate-waves).
// Round 13 = round 8's PROVEN always-LLC tagged bf16 ring, with the step
// reordered so the first LLC round trip is hidden under real work:
//   issue ring loads (no wait) -> stage Xs[t+1] -> 8 x-MFMAs from Xs[t]
//   -> vmcnt(0)+sched_barrier -> tag check/retry -> v_perm repack -> Hs
//   -> barrier -> 16 h-MFMAs -> gbuf -> barrier -> F -> publish.
// Protocol, swizzles, staging patterns, publish coalescing identical to R8.

#define SQ   512
#define BB   128
#define IN_  256
#define HH   512
#define RG   8
#define CGN  32
#define RINGHALF (BB * HH)     // dwords
#define RING_OFF 1024          // dwords (4 KB head, unused)

typedef float    f32x4 __attribute__((ext_vector_type(4)));
typedef short    s16x8 __attribute__((ext_vector_type(8)));
typedef unsigned u32x4 __attribute__((ext_vector_type(4)));

struct P {
  const float *x, *h0, *c0;
  const float *W[4], *bW[4], *U[4], *bU[4];   // gate order f,i,o,g
  float* out;        // [SQ][BB][HH] h_seq, then [BB][HH] h, then [BB][HH] c
  unsigned* ring;    // [2][BB][HH] tagged bf16 h (lo16=payload, hi16=tag)
  int mode;          // 0 = ring protocol, 2 = gridsync fallback (no ws)
};

__device__ __forceinline__ unsigned f2b(float f) {
  unsigned u = __float_as_uint(f);
  return (u + 0x7FFFu + ((u >> 16) & 1u)) >> 16;   // RNE f32->bf16
}
__device__ __forceinline__ float sigm(float x) { return 1.f / (1.f + __expf(-x)); }
__device__ __forceinline__ float tanh_(float x) {
  float e = __expf(-2.f * fabsf(x));
  float t = (1.f - e) / (1.f + e);
  return copysignf(t, x);
}
__device__ __forceinline__ u32x4 pack8(f32x4 a, f32x4 b) {
  u32x4 d;
  d.x = f2b(a.x) | (f2b(a.y) << 16);
  d.y = f2b(a.z) | (f2b(a.w) << 16);
  d.z = f2b(b.x) | (f2b(b.y) << 16);
  d.w = f2b(b.z) | (f2b(b.w) << 16);
  return d;
}
// (d0.lo16) | (d1.lo16 << 16) in one v_perm
__device__ __forceinline__ unsigned mergelo(unsigned d0, unsigned d1) {
  return __builtin_amdgcn_perm(d1, d0, 0x05040100u);
}

// Issue 8x dwordx4 from base+{0,256,...,1792}B, NO wait (overlap window).
#define ISSUE8_LLC(c0_,c1_,c2_,c3_,c4_,c5_,c6_,c7_,ptr_)                     \
  asm volatile(                                                              \
    "global_load_dwordx4 %0, %8, off sc0 sc1\n\t"                            \
    "global_load_dwordx4 %1, %8, off offset:256 sc0 sc1\n\t"                 \
    "global_load_dwordx4 %2, %8, off offset:512 sc0 sc1\n\t"                 \
    "global_load_dwordx4 %3, %8, off offset:768 sc0 sc1\n\t"                 \
    "global_load_dwordx4 %4, %8, off offset:1024 sc0 sc1\n\t"                \
    "global_load_dwordx4 %5, %8, off offset:1280 sc0 sc1\n\t"                \
    "global_load_dwordx4 %6, %8, off offset:1536 sc0 sc1\n\t"                \
    "global_load_dwordx4 %7, %8, off offset:1792 sc0 sc1"                    \
    : "=&v"(c0_), "=&v"(c1_), "=&v"(c2_), "=&v"(c3_),                        \
      "=&v"(c4_), "=&v"(c5_), "=&v"(c6_), "=&v"(c7_)                         \
    : "v"(ptr_) : "memory")

// Same 8 loads with ONE waitcnt (retry path, as round 8).
#define LOAD8_LLC(c0_,c1_,c2_,c3_,c4_,c5_,c6_,c7_,ptr_)                      \
  asm volatile(                                                              \
    "global_load_dwordx4 %0, %8, off sc0 sc1\n\t"                            \
    "global_load_dwordx4 %1, %8, off offset:256 sc0 sc1\n\t"                 \
    "global_load_dwordx4 %2, %8, off offset:512 sc0 sc1\n\t"                 \
    "global_load_dwordx4 %3, %8, off offset:768 sc0 sc1\n\t"                 \
    "global_load_dwordx4 %4, %8, off offset:1024 sc0 sc1\n\t"                \
    "global_load_dwordx4 %5, %8, off offset:1280 sc0 sc1\n\t"                \
    "global_load_dwordx4 %6, %8, off offset:1536 sc0 sc1\n\t"                \
    "global_load_dwordx4 %7, %8, off offset:1792 sc0 sc1\n\t"                \
    "s_waitcnt vmcnt(0)"                                                     \
    : "=&v"(c0_), "=&v"(c1_), "=&v"(c2_), "=&v"(c3_),                        \
      "=&v"(c4_), "=&v"(c5_), "=&v"(c6_), "=&v"(c7_)                         \
    : "v"(ptr_) : "memory")

__global__ void __launch_bounds__(256, 1) lstm_all(P p) {
  __shared__ unsigned short Hs[16][512];      // h bf16, rows 1024B, XOR swz
  __shared__ unsigned short Xs[2][16][256];   // x bf16 dbuf, rows 512B, XOR swz
  __shared__ float gbuf[4][16][17];

  const int tid = threadIdx.x;
  const int bid = blockIdx.x;
  const int r   = bid & 7;          // rowgroup
  const int cgi = bid >> 3;         // colgroup
  const int rb  = r * 16;
  const int hcb = cgi * 16;

  const int w   = tid >> 6;         // wave = gate (0=f,1=i,2=o,3=g)
  const int l   = tid & 63;
  const int l16 = l & 15;
  const int lk  = l >> 4;
  const int row16 = tid >> 4;       // staging/update row 0..15
  const int n16   = tid & 15;

  unsigned* ring = p.ring;          // valid only in mode 0

  // ---- per-wave B fragments (W|U) -> registers, bf16, once ----
  const int col = hcb + l16;
  s16x8 bfrag[24];
#pragma unroll
  for (int kk = 0; kk < 24; ++kk) {
    int k = kk * 32 + lk * 8;
    const float* src = (kk < 8) ? (p.W[w] + (size_t)col * IN_ + k)
                                : (p.U[w] + (size_t)col * HH + (k - IN_));
    f32x4 a = *(const f32x4*)src;
    f32x4 b = *(const f32x4*)(src + 4);
    s16x8 v;
    v[0]=(short)f2b(a.x); v[1]=(short)f2b(a.y); v[2]=(short)f2b(a.z); v[3]=(short)f2b(a.w);
    v[4]=(short)f2b(b.x); v[5]=(short)f2b(b.y); v[6]=(short)f2b(b.z); v[7]=(short)f2b(b.w);
    bfrag[kk] = v;
  }
  const float bias = p.bW[w][col] + p.bU[w][col];
  float cval = p.c0[(size_t)(rb + row16) * HH + hcb + n16];

  const int wswz = (row16 & 7) << 4;   // staging-row byte-XOR key
  const int rswz = (l16 & 7) << 4;     // mfma-read byte-XOR key
  char* HsB = (char*)&Hs[0][0];
  char* XsB = (char*)&Xs[0][0][0];

  // ---- prologue: stage Xs[0] from x(0); prefetch x(1) -> regs ----
  {
    const float* xs = p.x + (size_t)(rb + row16) * IN_ + n16 * 16;
    f32x4 a0 = *(const f32x4*)(xs);
    f32x4 b0 = *(const f32x4*)(xs + 4);
    f32x4 a1 = *(const f32x4*)(xs + 8);
    f32x4 b1 = *(const f32x4*)(xs + 12);
    char* xrow = XsB + row16 * 512;
    *(u32x4*)(xrow + ((n16 * 32)      ^ wswz)) = pack8(a0, b0);
    *(u32x4*)(xrow + ((n16 * 32 + 16) ^ wswz)) = pack8(a1, b1);
  }
  f32x4 xg0, xg1, xg2, xg3;
  {
    const float* xs = p.x + ((size_t)1 * BB + rb + row16) * IN_ + n16 * 16;
    xg0 = *(const f32x4*)(xs);
    xg1 = *(const f32x4*)(xs + 4);
    xg2 = *(const f32x4*)(xs + 8);
    xg3 = *(const f32x4*)(xs + 12);
  }
  __syncthreads();   // Xs[0] visible to all waves

  for (int t = 0; t < SQ; ++t) {
    // ---- 1) issue speculative ring loads (no wait) ----
    u32x4 c0, c1, c2, c3, c4, c5, c6, c7;
    const unsigned* hb = ring + (((t - 1) & 1) ? RINGHALF : 0)
                       + (size_t)(rb + row16) * HH + n16 * 4;
    const bool ringstep = (t > 0) && (p.mode == 0);
    if (ringstep) { ISSUE8_LLC(c0, c1, c2, c3, c4, c5, c6, c7, hb); }

    // ---- 2) stage Xs[(t+1)&1] from prefetched regs (fills load shadow) ----
    if (t + 1 < SQ) {
      char* xrow = XsB + ((t + 1) & 1) * 8192 + row16 * 512;
      *(u32x4*)(xrow + ((n16 * 32)      ^ wswz)) = pack8(xg0, xg1);
      *(u32x4*)(xrow + ((n16 * 32 + 16) ^ wswz)) = pack8(xg2, xg3);
    }

    // ---- 3) 8 x-MFMAs from Xs[t&1] (synced by barrier 1 of t-1) ----
    f32x4 acc0 = { bias, bias, bias, bias };
    f32x4 acc1 = { 0.f, 0.f, 0.f, 0.f };
    const char* xr = XsB + (t & 1) * 8192 + l16 * 512;
#pragma unroll
    for (int kp = 0; kp < 8; kp += 2) {
      s16x8 a0 = *(const s16x8*)(xr + ((kp * 64 + lk * 16)       ^ rswz));
      s16x8 a1 = *(const s16x8*)(xr + (((kp + 1) * 64 + lk * 16) ^ rswz));
      acc0 = __builtin_amdgcn_mfma_f32_16x16x32_bf16(a0, bfrag[kp],     acc0, 0, 0, 0);
      acc1 = __builtin_amdgcn_mfma_f32_16x16x32_bf16(a1, bfrag[kp + 1], acc1, 0, 0, 0);
    }

    // ---- 4) finalize h_{t-1} into Hs (bf16, swizzled) ----
    char* hrow = HsB + row16 * 1024;
    if (t == 0) {
      const float* src = p.h0 + (size_t)(rb + row16) * HH + n16 * 4;
#pragma unroll
      for (int cc = 0; cc < 8; ++cc) {
        f32x4 v = *(const f32x4*)(src + cc * 64);
        unsigned lo = f2b(v.x) | (f2b(v.y) << 16);
        unsigned hi = f2b(v.z) | (f2b(v.w) << 16);
        int boff = ((cc * 128 + n16 * 8) ^ wswz);
        *(uint2*)(hrow + boff) = make_uint2(lo, hi);
      }
    } else if (p.mode == 0) {
      asm volatile("s_waitcnt vmcnt(0)" ::: "memory");
      __builtin_amdgcn_sched_barrier(0);   // rule #18: pin tag check after wait
      const unsigned tg = (unsigned)t;
#define TAGOK(v) (((v).x >> 16) == tg && ((v).y >> 16) == tg && \
                  ((v).z >> 16) == tg && ((v).w >> 16) == tg)
      int spin = 0;
      for (;;) {
        if (TAGOK(c0) && TAGOK(c1) && TAGOK(c2) && TAGOK(c3) &&
            TAGOK(c4) && TAGOK(c5) && TAGOK(c6) && TAGOK(c7)) break;
        if (++spin > (1 << 16)) break;   // bounded: fail loud, never hang
        if (spin > 8) __builtin_amdgcn_s_sleep(1);
        LOAD8_LLC(c0, c1, c2, c3, c4, c5, c6, c7, hb);
        __builtin_amdgcn_sched_barrier(0);
      }
#undef TAGOK
      u32x4 cv[8] = {c0, c1, c2, c3, c4, c5, c6, c7};
#pragma unroll
      for (int cc = 0; cc < 8; ++cc) {
        uint2 u = make_uint2(mergelo(cv[cc].x, cv[cc].y),
                             mergelo(cv[cc].z, cv[cc].w));
        int boff = ((cc * 128 + n16 * 8) ^ wswz);
        *(uint2*)(hrow + boff) = u;
      }
    } else {
      // gridsync fallback: f32 h from d_out via LLC
      cg::this_grid().sync();
      const float* hp = p.out + ((size_t)(t - 1) * BB + rb + row16) * HH + n16 * 4;
      u32x4 a0, a1, a2, a3, a4, a5, a6, a7;
      LOAD8_LLC(a0, a1, a2, a3, a4, a5, a6, a7, hp);
      u32x4 av[8] = {a0, a1, a2, a3, a4, a5, a6, a7};
#pragma unroll
      for (int cc = 0; cc < 8; ++cc) {
        unsigned lo = f2b(__uint_as_float(av[cc].x)) | (f2b(__uint_as_float(av[cc].y)) << 16);
        unsigned hi = f2b(__uint_as_float(av[cc].z)) | (f2b(__uint_as_float(av[cc].w)) << 16);
        int boff = ((cc * 128 + n16 * 8) ^ wswz);
        *(uint2*)(hrow + boff) = make_uint2(lo, hi);
      }
    }

    // ---- 4.5) prefetch x(t+2) -> regs (consumed at step t+1 phase 2) ----
    if (t + 2 < SQ) {
      const float* xs = p.x + ((size_t)(t + 2) * BB + rb + row16) * IN_ + n16 * 16;
      xg0 = *(const f32x4*)(xs);
      xg1 = *(const f32x4*)(xs + 4);
      xg2 = *(const f32x4*)(xs + 8);
      xg3 = *(const f32x4*)(xs + 12);
    }
    __syncthreads();   // barrier 1: Hs (+ Xs[(t+1)&1]) ready

    // ---- 6) 16 h-MFMAs ----
    const char* hr = HsB + l16 * 1024;
#pragma unroll
    for (int kp = 0; kp < 16; kp += 2) {
      s16x8 a0 = *(const s16x8*)(hr + ((kp * 64 + lk * 16)       ^ rswz));
      s16x8 a1 = *(const s16x8*)(hr + (((kp + 1) * 64 + lk * 16) ^ rswz));
      acc0 = __builtin_amdgcn_mfma_f32_16x16x32_bf16(a0, bfrag[8 + kp], acc0, 0, 0, 0);
      acc1 = __builtin_amdgcn_mfma_f32_16x16x32_bf16(a1, bfrag[9 + kp], acc1, 0, 0, 0);
    }

    // ---- 7) activations -> gbuf (D-frag: row=lk*4+rr, col=l16) ----
#pragma unroll
    for (int rr = 0; rr < 4; ++rr) {
      float v = acc0[rr] + acc1[rr];
      v = (w < 3) ? sigm(v) : tanh_(v);
      gbuf[w][lk * 4 + rr][l16] = v;
    }
    __syncthreads();   // barrier 2: gbuf ready

    // ---- 8) cell update + publish (coalesced, as round 8) ----
    float f = gbuf[0][row16][n16];
    float i = gbuf[1][row16][n16];
    float o = gbuf[2][row16][n16];
    float g = gbuf[3][row16][n16];
    cval = f * cval + i * g;
    float h = o * tanh_(cval);

    size_t oidx = ((size_t)t * BB + rb + row16) * HH + hcb + n16;
    if (p.mode == 0) {
      unsigned tw = ((unsigned)(t + 1) << 16) | f2b(h);
      unsigned* dst = ring + ((t & 1) ? RINGHALF : 0)
                    + (size_t)(rb + row16) * HH + hcb + n16;
      asm volatile("global_store_dword %0, %1, off sc0 sc1"
                   :: "v"(dst), "v"(tw) : "memory");
      __builtin_nontemporal_store(h, p.out + oidx);
    } else {
      asm volatile("global_store_dword %0, %1, off sc0 sc1"
                   :: "v"(p.out + oidx), "v"(h) : "memory");
      asm volatile("s_waitcnt vmcnt(0)" ::: "memory");
    }
    if (t == SQ - 1) {
      size_t base = (size_t)SQ * BB * HH;
      size_t idx2 = (size_t)(rb + row16) * HH + hcb + n16;
      p.out[base + idx2] = h;
      p.out[base + (size_t)BB * HH + idx2] = cval;
    }
    // reuse safety: Hs written next iter only after barrier 2 of this iter;
    // Xs[(t+1)&1] written this iter, read next iter after this barrier 1;
    // gbuf rewritten next iter after next barrier 1. Ring WAR safe (2-deep
    // ring + transitive step dependency, as round 8).
  }
}

extern "C" void kernel_launch(void* const* d_in, const int* in_sizes, int n_in,
                              void* d_out, int out_size, void* d_ws, size_t ws_size,
                              hipStream_t stream) {
  P p;
  p.x  = (const float*)d_in[0];
  p.h0 = (const float*)d_in[1];
  p.c0 = (const float*)d_in[2];
  for (int g = 0; g < 4; ++g) {
    p.W[g]  = (const float*)d_in[3 + 4 * g];
    p.bW[g] = (const float*)d_in[4 + 4 * g];
    p.U[g]  = (const float*)d_in[5 + 4 * g];
    p.bU[g] = (const float*)d_in[6 + 4 * g];
  }
  p.out = (float*)d_out;

  const size_t need = (size_t)(RING_OFF + 2 * BB * HH) * sizeof(unsigned);
  const bool ws_ok = (d_ws != nullptr) && (ws_size >= need);
  p.mode = ws_ok ? 0 : 2;
  p.ring = ws_ok ? ((unsigned*)d_ws + RING_OFF) : nullptr;
  if (ws_ok) hipMemsetAsync(d_ws, 0, need, stream);   // tags=0: never valid

  void* args[] = { &p };
  hipError_t e = hipLaunchCooperativeKernel((const void*)lstm_all,
                                            dim3(RG * CGN), dim3(256),
                                            args, 0, stream);
  if (e != hipSuccess) {
    // plain launch: 256 blocks at 1/CU are co-resident; ring protocol valid
    hipLaunchKernelGGL(lstm_all, dim3(RG * CGN), dim3(256), 0, stream, p);
  }
}

// Round 14
// 1290.982 us; speedup vs baseline: 1.5487x; 1.5487x over previous
//
#include <hip/hip_runtime.h>
#include <hip/hip_cooperative_groups.h>

namespace cg = cooperative_groups;

// LSTM S=512,B=128,IN=256,H=512 — persistent kernel, 256 blocks =
// 8 rowgroups(16 batch rows) x 32 colgroups(16 hidden cols; 4 gate-waves).
// Round 14 = round 8 BIT-EXACT in protocol/order/memory patterns (proven
// 1297us), plus two strictly register-local micro-opts:
//   (1) 4 MFMA accumulator chains (dependency depth 12 -> 6)
//   (2) v_perm repack of ring payload (verified identical in R13)

#define SQ   512
#define BB   128
#define IN_  256
#define HH   512
#define RG   8
#define CGN  32
#define RINGHALF (BB * HH)     // dwords
#define RING_OFF 1024          // dwords (4 KB head, unused)

typedef float    f32x4 __attribute__((ext_vector_type(4)));
typedef short    s16x8 __attribute__((ext_vector_type(8)));
typedef unsigned u32x4 __attribute__((ext_vector_type(4)));

struct P {
  const float *x, *h0, *c0;
  const float *W[4], *bW[4], *U[4], *bU[4];   // gate order f,i,o,g
  float* out;        // [SQ][BB][HH] h_seq, then [BB][HH] h, then [BB][HH] c
  unsigned* ring;    // [2][BB][HH] tagged bf16 h (lo16=payload, hi16=tag)
  int mode;          // 0 = ring protocol, 2 = gridsync fallback (no ws)
};

__device__ __forceinline__ unsigned f2b(float f) {
  unsigned u = __float_as_uint(f);
  return (u + 0x7FFFu + ((u >> 16) & 1u)) >> 16;   // RNE f32->bf16
}
__device__ __forceinline__ float sigm(float x) { return 1.f / (1.f + __expf(-x)); }
__device__ __forceinline__ float tanh_(float x) {
  float e = __expf(-2.f * fabsf(x));
  float t = (1.f - e) / (1.f + e);
  return copysignf(t, x);
}
__device__ __forceinline__ u32x4 pack8(f32x4 a, f32x4 b) {
  u32x4 d;
  d.x = f2b(a.x) | (f2b(a.y) << 16);
  d.y = f2b(a.z) | (f2b(a.w) << 16);
  d.z = f2b(b.x) | (f2b(b.y) << 16);
  d.w = f2b(b.z) | (f2b(b.w) << 16);
  return d;
}
// (d0.lo16) | (d1.lo16 << 16) in one v_perm (bytes 0-3 from src1, 4-7 from src0)
__device__ __forceinline__ unsigned mergelo(unsigned d0, unsigned d1) {
  return __builtin_amdgcn_perm(d1, d0, 0x05040100u);
}

// 8x dwordx4 from base+{0,256,...,1792}B, ONE waitcnt, LLC-coherent.
#define LOAD8_LLC(c0_,c1_,c2_,c3_,c4_,c5_,c6_,c7_,ptr_)                      \
  asm volatile(                                                              \
    "global_load_dwordx4 %0, %8, off sc0 sc1\n\t"                            \
    "global_load_dwordx4 %1, %8, off offset:256 sc0 sc1\n\t"                 \
    "global_load_dwordx4 %2, %8, off offset:512 sc0 sc1\n\t"                 \
    "global_load_dwordx4 %3, %8, off offset:768 sc0 sc1\n\t"                 \
    "global_load_dwordx4 %4, %8, off offset:1024 sc0 sc1\n\t"                \
    "global_load_dwordx4 %5, %8, off offset:1280 sc0 sc1\n\t"                \
    "global_load_dwordx4 %6, %8, off offset:1536 sc0 sc1\n\t"                \
    "global_load_dwordx4 %7, %8, off offset:1792 sc0 sc1\n\t"                \
    "s_waitcnt vmcnt(0)"                                                     \
    : "=&v"(c0_), "=&v"(c1_), "=&v"(c2_), "=&v"(c3_),                        \
      "=&v"(c4_), "=&v"(c5_), "=&v"(c6_), "=&v"(c7_)                         \
    : "v"(ptr_) : "memory")

__global__ void __launch_bounds__(256, 1) lstm_all(P p) {
  __shared__ unsigned short Hs[16][512];      // h bf16, rows 1024B, XOR swz
  __shared__ unsigned short Xs[2][16][256];   // x bf16 dbuf, rows 512B, XOR swz
  __shared__ float gbuf[4][16][17];

  const int tid = threadIdx.x;
  const int bid = blockIdx.x;
  const int r   = bid & 7;          // rowgroup
  const int cgi = bid >> 3;         // colgroup
  const int rb  = r * 16;
  const int hcb = cgi * 16;

  const int w   = tid >> 6;         // wave = gate (0=f,1=i,2=o,3=g)
  const int l   = tid & 63;
  const int l16 = l & 15;
  const int lk  = l >> 4;
  const int row16 = tid >> 4;       // staging/update row 0..15
  const int n16   = tid & 15;

  unsigned* ring = p.ring;          // valid only in mode 0

  // ---- per-wave B fragments (W|U) -> registers, bf16, once ----
  const int col = hcb + l16;
  s16x8 bfrag[24];
#pragma unroll
  for (int kk = 0; kk < 24; ++kk) {
    int k = kk * 32 + lk * 8;
    const float* src = (kk < 8) ? (p.W[w] + (size_t)col * IN_ + k)
                                : (p.U[w] + (size_t)col * HH + (k - IN_));
    f32x4 a = *(const f32x4*)src;
    f32x4 b = *(const f32x4*)(src + 4);
    s16x8 v;
    v[0]=(short)f2b(a.x); v[1]=(short)f2b(a.y); v[2]=(short)f2b(a.z); v[3]=(short)f2b(a.w);
    v[4]=(short)f2b(b.x); v[5]=(short)f2b(b.y); v[6]=(short)f2b(b.z); v[7]=(short)f2b(b.w);
    bfrag[kk] = v;
  }
  const float bias = p.bW[w][col] + p.bU[w][col];
  float cval = p.c0[(size_t)(rb + row16) * HH + hcb + n16];

  const int wswz = (row16 & 7) << 4;   // staging-row byte-XOR key
  const int rswz = (l16 & 7) << 4;     // mfma-read byte-XOR key
  char* HsB = (char*)&Hs[0][0];
  char* XsB = (char*)&Xs[0][0][0];

  // ---- prologue: x(t=0) into registers ----
  f32x4 xg0, xg1, xg2, xg3;
  {
    const float* xs = p.x + (size_t)(rb + row16) * IN_ + n16 * 16;
    xg0 = *(const f32x4*)(xs);
    xg1 = *(const f32x4*)(xs + 4);
    xg2 = *(const f32x4*)(xs + 8);
    xg3 = *(const f32x4*)(xs + 12);
  }

  for (int t = 0; t < SQ; ++t) {
    // ---- A) Xs[t&1] <- xreg; issue x(t+1) loads (hide under ring read) ----
    {
      char* xrow = XsB + (t & 1) * 8192 + row16 * 512;
      *(u32x4*)(xrow + ((n16 * 32)      ^ wswz)) = pack8(xg0, xg1);
      *(u32x4*)(xrow + ((n16 * 32 + 16) ^ wswz)) = pack8(xg2, xg3);
      if (t + 1 < SQ) {
        const float* xs = p.x + ((size_t)(t + 1) * BB + rb + row16) * IN_ + n16 * 16;
        xg0 = *(const f32x4*)(xs);
        xg1 = *(const f32x4*)(xs + 4);
        xg2 = *(const f32x4*)(xs + 8);
        xg3 = *(const f32x4*)(xs + 12);
      }
    }

    // ---- B) obtain h_{t-1} into Hs (bf16, swizzled) — tagged LLC ring ----
    char* hrow = HsB + row16 * 1024;
    if (t == 0) {
      const float* src = p.h0 + (size_t)(rb + row16) * HH + n16 * 4;
#pragma unroll
      for (int cc = 0; cc < 8; ++cc) {
        f32x4 v = *(const f32x4*)(src + cc * 64);
        unsigned lo = f2b(v.x) | (f2b(v.y) << 16);
        unsigned hi = f2b(v.z) | (f2b(v.w) << 16);
        int boff = ((cc * 128 + n16 * 8) ^ wswz);
        *(uint2*)(hrow + boff) = make_uint2(lo, hi);
      }
    } else if (p.mode == 0) {
      const unsigned* hb = ring + (((t - 1) & 1) ? RINGHALF : 0)
                         + (size_t)(rb + row16) * HH + n16 * 4;
      u32x4 c0,c1,c2,c3,c4,c5,c6,c7;
      const unsigned tg = (unsigned)t;
#define TAGOK(v) (((v).x >> 16) == tg && ((v).y >> 16) == tg && \
                  ((v).z >> 16) == tg && ((v).w >> 16) == tg)
      int spin = 0;
      for (;;) {
        LOAD8_LLC(c0,c1,c2,c3,c4,c5,c6,c7,hb);
        if (TAGOK(c0) && TAGOK(c1) && TAGOK(c2) && TAGOK(c3) &&
            TAGOK(c4) && TAGOK(c5) && TAGOK(c6) && TAGOK(c7)) break;
        if (++spin > (1 << 16)) break;   // bounded: fail loud, never hang
        if (spin > 8) __builtin_amdgcn_s_sleep(1);
      }
#undef TAGOK
      u32x4 cv[8] = {c0,c1,c2,c3,c4,c5,c6,c7};
#pragma unroll
      for (int cc = 0; cc < 8; ++cc) {
        uint2 u = make_uint2(mergelo(cv[cc].x, cv[cc].y),
                             mergelo(cv[cc].z, cv[cc].w));
        int boff = ((cc * 128 + n16 * 8) ^ wswz);
        *(uint2*)(hrow + boff) = u;
      }
    } else {
      // gridsync fallback: f32 h from d_out via LLC
      cg::this_grid().sync();
      const float* hp = p.out + ((size_t)(t - 1) * BB + rb + row16) * HH + n16 * 4;
      u32x4 a0,a1,a2,a3,a4,a5,a6,a7;
      LOAD8_LLC(a0,a1,a2,a3,a4,a5,a6,a7,hp);
      u32x4 av[8] = {a0,a1,a2,a3,a4,a5,a6,a7};
#pragma unroll
      for (int cc = 0; cc < 8; ++cc) {
        unsigned lo = f2b(__uint_as_float(av[cc].x)) | (f2b(__uint_as_float(av[cc].y)) << 16);
        unsigned hi = f2b(__uint_as_float(av[cc].z)) | (f2b(__uint_as_float(av[cc].w)) << 16);
        int boff = ((cc * 128 + n16 * 8) ^ wswz);
        *(uint2*)(hrow + boff) = make_uint2(lo, hi);
      }
    }
    __syncthreads();   // barrier 1: Xs[t&1] + Hs ready

    // ---- D) 24 MFMAs: 8 from Xs, 16 from Hs — FOUR accumulator chains ----
    f32x4 acc0 = { bias, bias, bias, bias };
    f32x4 acc1 = { 0.f, 0.f, 0.f, 0.f };
    f32x4 acc2 = { 0.f, 0.f, 0.f, 0.f };
    f32x4 acc3 = { 0.f, 0.f, 0.f, 0.f };
    const char* xr = XsB + (t & 1) * 8192 + l16 * 512;
    const char* hr = HsB + l16 * 1024;
#pragma unroll
    for (int kp = 0; kp < 8; kp += 4) {
      s16x8 a0 = *(const s16x8*)(xr + (((kp + 0) * 64 + lk * 16) ^ rswz));
      s16x8 a1 = *(const s16x8*)(xr + (((kp + 1) * 64 + lk * 16) ^ rswz));
      s16x8 a2 = *(const s16x8*)(xr + (((kp + 2) * 64 + lk * 16) ^ rswz));
      s16x8 a3 = *(const s16x8*)(xr + (((kp + 3) * 64 + lk * 16) ^ rswz));
      acc0 = __builtin_amdgcn_mfma_f32_16x16x32_bf16(a0, bfrag[kp],     acc0, 0, 0, 0);
      acc1 = __builtin_amdgcn_mfma_f32_16x16x32_bf16(a1, bfrag[kp + 1], acc1, 0, 0, 0);
      acc2 = __builtin_amdgcn_mfma_f32_16x16x32_bf16(a2, bfrag[kp + 2], acc2, 0, 0, 0);
      acc3 = __builtin_amdgcn_mfma_f32_16x16x32_bf16(a3, bfrag[kp + 3], acc3, 0, 0, 0);
    }
#pragma unroll
    for (int kp = 0; kp < 16; kp += 4) {
      s16x8 a0 = *(const s16x8*)(hr + (((kp + 0) * 64 + lk * 16) ^ rswz));
      s16x8 a1 = *(const s16x8*)(hr + (((kp + 1) * 64 + lk * 16) ^ rswz));
      s16x8 a2 = *(const s16x8*)(hr + (((kp + 2) * 64 + lk * 16) ^ rswz));
      s16x8 a3 = *(const s16x8*)(hr + (((kp + 3) * 64 + lk * 16) ^ rswz));
      acc0 = __builtin_amdgcn_mfma_f32_16x16x32_bf16(a0, bfrag[8 + kp],  acc0, 0, 0, 0);
      acc1 = __builtin_amdgcn_mfma_f32_16x16x32_bf16(a1, bfrag[9 + kp],  acc1, 0, 0, 0);
      acc2 = __builtin_amdgcn_mfma_f32_16x16x32_bf16(a2, bfrag[10 + kp], acc2, 0, 0, 0);
      acc3 = __builtin_amdgcn_mfma_f32_16x16x32_bf16(a3, bfrag[11 + kp], acc3, 0, 0, 0);
    }

    // ---- E) activations -> gbuf (D-frag: row=lk*4+rr, col=l16) ----
#pragma unroll
    for (int rr = 0; rr < 4; ++rr) {
      float v = (acc0[rr] + acc1[rr]) + (acc2[rr] + acc3[rr]);
      v = (w < 3) ? sigm(v) : tanh_(v);
      gbuf[w][lk * 4 + rr][l16] = v;
    }
    __syncthreads();   // barrier 2: gbuf ready

    // ---- F) cell update + publish (coalesced, as round 8) ----
    float f = gbuf[0][row16][n16];
    float i = gbuf[1][row16][n16];
    float o = gbuf[2][row16][n16];
    float g = gbuf[3][row16][n16];
    cval = f * cval + i * g;
    float h = o * tanh_(cval);

    size_t oidx = ((size_t)t * BB + rb + row16) * HH + hcb + n16;
    if (p.mode == 0) {
      unsigned tw = ((unsigned)(t + 1) << 16) | f2b(h);
      unsigned* dst = ring + ((t & 1) ? RINGHALF : 0)
                    + (size_t)(rb + row16) * HH + hcb + n16;
      asm volatile("global_store_dword %0, %1, off sc0 sc1"
                   :: "v"(dst), "v"(tw) : "memory");
      __builtin_nontemporal_store(h, p.out + oidx);
    } else {
      asm volatile("global_store_dword %0, %1, off sc0 sc1"
                   :: "v"(p.out + oidx), "v"(h) : "memory");
      asm volatile("s_waitcnt vmcnt(0)" ::: "memory");
    }
    if (t == SQ - 1) {
      size_t base = (size_t)SQ * BB * HH;
      size_t idx2 = (size_t)(rb + row16) * HH + hcb + n16;
      p.out[base + idx2] = h;
      p.out[base + (size_t)BB * HH + idx2] = cval;
    }
    // next iteration's post-B __syncthreads covers Hs/gbuf/Xs reuse
  }
}

extern "C" void kernel_launch(void* const* d_in, const int* in_sizes, int n_in,
                              void* d_out, int out_size, void* d_ws, size_t ws_size,
                              hipStream_t stream) {
  P p;
  p.x  = (const float*)d_in[0];
  p.h0 = (const float*)d_in[1];
  p.c0 = (const float*)d_in[2];
  for (int g = 0; g < 4; ++g) {
    p.W[g]  = (const float*)d_in[3 + 4 * g];
    p.bW[g] = (const float*)d_in[4 + 4 * g];
    p.U[g]  = (const float*)d_in[5 + 4 * g];
    p.bU[g] = (const float*)d_in[6 + 4 * g];
  }
  p.out = (float*)d_out;

  const size_t need = (size_t)(RING_OFF + 2 * BB * HH) * sizeof(unsigned);
  const bool ws_ok = (d_ws != nullptr) && (ws_size >= need);
  p.mode = ws_ok ? 0 : 2;
  p.ring = ws_ok ? ((unsigned*)d_ws + RING_OFF) : nullptr;
  if (ws_ok) hipMemsetAsync(d_ws, 0, need, stream);   // tags=0: never valid

  void* args[] = { &p };
  hipError_t e = hipLaunchCooperativeKernel((const void*)lstm_all,
                                            dim3(RG * CGN), dim3(256),
                                            args, 0, stream);
  if (e != hipSuccess) {
    // plain launch: 256 blocks at 1/CU are co-resident; ring protocol valid
    hipLaunchKernelGGL(lstm_all, dim3(RG * CGN), dim3(256), 0, stream, p);
  }
}